// Round 2
// baseline (398.708 us; speedup 1.0000x reference)
//
#include <hip/hip_runtime.h>
#include <hip/hip_cooperative_groups.h>

namespace cg = cooperative_groups;

// out[i,:] = mean_j(x[j,:]) @ Wv for all i (softmax with 2^-50 scale is exactly
// uniform in fp32). Single cooperative kernel:
//   P1: partial column sums of x   (32MB read, 4MB partial write)
//   P2: reduce partials -> colsum  (4MB, L2)   + zero outrow
//   P3: matvec colsum @ Wv -> outrow (4MB Wv read, 64-way atomics)
//   P4: broadcast outrow to all 8192 rows (32MB write)

#define NROWS 8192
#define DDIM  1024
#define NBLK  1024
#define RPB   (NROWS / NBLK)   // 8 rows per block in P1/P4

__global__ __launch_bounds__(256, 4) void fused_attn_k(
    const float4* __restrict__ x4, const float* __restrict__ Wv,
    float4* __restrict__ out4, float* __restrict__ ws) {
  cg::grid_group grid = cg::this_grid();
  const int t = threadIdx.x;
  const int b = blockIdx.x;

  float* partial = ws;                          // [1024][1024] floats, 4 MB
  float* colsum  = ws + (size_t)NBLK * DDIM;    // 1024 floats
  float* outrow  = colsum + DDIM;               // 1024 floats

  __shared__ float red[256];

  // ---- P1: block b sums rows [b*8, b*8+8), thread t owns float4 col-group t
  {
    const float4* p = x4 + (size_t)b * RPB * (DDIM / 4) + t;
    float4 acc = make_float4(0.f, 0.f, 0.f, 0.f);
#pragma unroll
    for (int r = 0; r < RPB; ++r) {
      float4 v = p[(size_t)r * (DDIM / 4)];
      acc.x += v.x; acc.y += v.y; acc.z += v.z; acc.w += v.w;
    }
    ((float4*)partial)[b * (DDIM / 4) + t] = acc;
  }
  grid.sync();

  // ---- P2: 64 blocks reduce 1024 partials -> colsum; block 64 zeroes outrow
  if (b < 64) {
    const int kk = t & 15;          // k within this block's 16-k chunk
    const int bg = t >> 4;          // which 64-partial slice
    const int k  = b * 16 + kk;
    float s = 0.f;
#pragma unroll 8
    for (int i = 0; i < 64; ++i) {
      s += partial[(size_t)(bg * 64 + i) * DDIM + k];
    }
    red[t] = s;
    __syncthreads();
    if (t < 128) red[t] += red[t + 128];
    __syncthreads();
    if (t < 64)  red[t] += red[t + 64];
    __syncthreads();
    if (t < 32)  red[t] += red[t + 32];
    __syncthreads();
    if (t < 16)  colsum[b * 16 + t] = red[t] + red[t + 16];
  } else if (b == 64) {
    for (int i = t; i < DDIM; i += 256) outrow[i] = 0.f;
  }
  grid.sync();

  // ---- P3: 256 blocks matvec. block = (kc, dc): 16 k's x 256 d's.
  if (b < 256) {
    const int kc = b >> 2;
    const int dc = b & 3;
    const int k0 = kc * 16;
    const int d  = dc * 256 + t;
    float acc = 0.f;
#pragma unroll
    for (int k = 0; k < 16; ++k) {
      acc += colsum[k0 + k] * Wv[(size_t)(k0 + k) * DDIM + d];
    }
    atomicAdd(&outrow[d], acc * (1.0f / (float)NROWS));
  }
  grid.sync();

  // ---- P4: broadcast outrow into rows [b*8, b*8+8)
  {
    const float4 v = ((const float4*)outrow)[t];
    float4* p = out4 + (size_t)b * RPB * (DDIM / 4) + t;
#pragma unroll
    for (int r = 0; r < RPB; ++r) {
      p[(size_t)r * (DDIM / 4)] = v;
    }
  }
}

extern "C" void kernel_launch(void* const* d_in, const int* in_sizes, int n_in,
                              void* d_out, int out_size, void* d_ws, size_t ws_size,
                              hipStream_t stream) {
  const float4* x4 = (const float4*)d_in[0];
  // d_in[1] = Wq, d_in[2] = Wk provably unused (softmax exactly uniform).
  const float*  Wv = (const float*)d_in[3];
  float4* out4 = (float4*)d_out;
  float*  ws   = (float*)d_ws;

  void* args[] = { (void*)&x4, (void*)&Wv, (void*)&out4, (void*)&ws };
  hipLaunchCooperativeKernel((void*)fused_attn_k, dim3(NBLK), dim3(256),
                             args, 0, stream);
}

// Round 3
// 194.331 us; speedup vs baseline: 2.0517x; 2.0517x over previous
//
#include <hip/hip_runtime.h>

// out[i,:] = mean_j(x[j,:]) @ Wv for all i (softmax with 2^-50 scale is exactly
// uniform in fp32; exp(|s|<6e-13) == 1.0f exactly). Q/K/Wq/Wk are dead.
//
// R2 post-mortem: grid.sync() costs ~100us each on MI355X (VALUBusy 0.24%,
// 315us for 12us of memory work). Use stream-ordered kernels instead.

#define NROWS 8192
#define DDIM  1024

// ws layout (floats): [0..1023] colsum, [1024..2047] outrow. Zeroed by memset.

// K1: column sums. 1024 blocks x 256 thr (4 blocks/CU, 16 waves/CU for BW).
// Block b sums rows [8b, 8b+8); thread t owns float4 col-group t (coalesced).
__global__ __launch_bounds__(256) void colsum_k(const float4* __restrict__ x4,
                                                float* __restrict__ colsum) {
  const int t = threadIdx.x;
  const int b = blockIdx.x;
  const float4* p = x4 + (size_t)b * 8 * (DDIM / 4) + t;
  float4 acc = make_float4(0.f, 0.f, 0.f, 0.f);
#pragma unroll
  for (int r = 0; r < 8; ++r) {   // 8 independent 16B loads in flight
    float4 v = p[(size_t)r * (DDIM / 4)];
    acc.x += v.x; acc.y += v.y; acc.z += v.z; acc.w += v.w;
  }
  atomicAdd(&colsum[4 * t + 0], acc.x);
  atomicAdd(&colsum[4 * t + 1], acc.y);
  atomicAdd(&colsum[4 * t + 2], acc.z);
  atomicAdd(&colsum[4 * t + 3], acc.w);
}

// K2: outrow[d] = (1/8192) * sum_k colsum[k] * Wv[k][d].
// 512 blocks: kc = b>>2 (8 k's each), dc = b&3 (256 d's each). Coalesced Wv rows.
__global__ __launch_bounds__(256) void matvec_k(const float* __restrict__ Wv,
                                                const float* __restrict__ colsum,
                                                float* __restrict__ outrow) {
  const int t  = threadIdx.x;
  const int kc = blockIdx.x >> 2;
  const int dc = blockIdx.x & 3;
  const int k0 = kc * 8;
  const int d  = dc * 256 + t;
  float acc = 0.f;
#pragma unroll
  for (int k = 0; k < 8; ++k) {
    acc += colsum[k0 + k] * Wv[(size_t)(k0 + k) * DDIM + d];
  }
  atomicAdd(&outrow[d], acc * (1.0f / (float)NROWS));
}

// K3: broadcast outrow into all rows. 2048 blocks x 256 thr, 4 rows/block.
__global__ __launch_bounds__(256) void bcast_k(const float4* __restrict__ outrow4,
                                               float4* __restrict__ out4) {
  const int t = threadIdx.x;
  const int b = blockIdx.x;
  const float4 v = outrow4[t];
  float4* p = out4 + (size_t)b * 4 * (DDIM / 4) + t;
#pragma unroll
  for (int r = 0; r < 4; ++r) {
    p[(size_t)r * (DDIM / 4)] = v;
  }
}

extern "C" void kernel_launch(void* const* d_in, const int* in_sizes, int n_in,
                              void* d_out, int out_size, void* d_ws, size_t ws_size,
                              hipStream_t stream) {
  const float* x  = (const float*)d_in[0];
  // d_in[1] = Wq, d_in[2] = Wk provably unused (softmax exactly uniform).
  const float* Wv = (const float*)d_in[3];
  float* ws     = (float*)d_ws;
  float* colsum = ws;          // 1024 floats
  float* outrow = ws + DDIM;   // 1024 floats

  hipMemsetAsync(ws, 0, 2 * DDIM * sizeof(float), stream);
  hipLaunchKernelGGL(colsum_k, dim3(1024), dim3(256), 0, stream,
                     (const float4*)x, colsum);
  hipLaunchKernelGGL(matvec_k, dim3(512), dim3(256), 0, stream,
                     Wv, colsum, outrow);
  hipLaunchKernelGGL(bcast_k, dim3(2048), dim3(256), 0, stream,
                     (const float4*)outrow, (float4*)d_out);
}

// Round 4
// 102.890 us; speedup vs baseline: 3.8751x; 1.8887x over previous
//
#include <hip/hip_runtime.h>

// out[i,:] = mean_j(x[j,:]) @ Wv for all i (softmax with 2^-50 scale is exactly
// uniform in fp32; exp(|s|<6e-13) == 1.0f exactly). Q/K/Wq/Wk are dead.
//
// R2 post-mortem: grid.sync() ~100us each on MI355X -> stream-ordered kernels.
// R3 post-mortem: global atomicAdd = memory-side RMW, ~100ns per same-address
// op serialized (1M atomics / 1024 addrs = depth 1024 = 104us). This version
// has ZERO global atomics: every global address is written exactly once.

#define NROWS 8192
#define DDIM  1024

// ws layout (floats): [0 .. 1024*1024) partial, then [+0..1024) colsum,
// [+1024..2048) outrow.

// K1: block b sums rows [8b, 8b+8) -> partial[b][:]. Coalesced float4.
__global__ __launch_bounds__(256) void colsum_part_k(
    const float4* __restrict__ x4, float4* __restrict__ partial4) {
  const int t = threadIdx.x;
  const int b = blockIdx.x;
  const float4* p = x4 + (size_t)b * 8 * (DDIM / 4) + t;
  float4 acc = make_float4(0.f, 0.f, 0.f, 0.f);
#pragma unroll
  for (int r = 0; r < 8; ++r) {
    float4 v = p[(size_t)r * (DDIM / 4)];
    acc.x += v.x; acc.y += v.y; acc.z += v.z; acc.w += v.w;
  }
  partial4[(size_t)b * (DDIM / 4) + t] = acc;
}

// K2: 64 blocks; block i owns k in [16i, 16i+16).
// Thread t = (bl = t>>4, kl = t&15): sums partial[bl + 16j][k0+kl], j=0..63,
// then LDS-reduces the 16 bl lanes. Writes colsum[k] (scaled 1/NROWS) ONCE.
__global__ __launch_bounds__(256) void colsum_red_k(
    const float* __restrict__ partial, float* __restrict__ colsum) {
  __shared__ float red[256];
  const int t  = threadIdx.x;
  const int k0 = blockIdx.x * 16;
  const int kl = t & 15;
  const int bl = t >> 4;
  float s = 0.f;
#pragma unroll 8
  for (int j = 0; j < 64; ++j) {
    s += partial[(size_t)(bl + 16 * j) * DDIM + (k0 + kl)];
  }
  red[t] = s;
  __syncthreads();
  if (t < 128) red[t] += red[t + 128];
  __syncthreads();
  if (t < 64)  red[t] += red[t + 64];
  __syncthreads();
  if (t < 32)  red[t] += red[t + 32];
  __syncthreads();
  if (t < 16)  colsum[k0 + t] = (red[t] + red[t + 16]) * (1.0f / (float)NROWS);
}

// K3: 64 blocks; block i owns d in [16i, 16i+16).
// Thread t = (kl = t>>4, dl = t&15): acc += colsum[kl+16j] * Wv[kl+16j][d0+dl],
// j=0..63, then LDS-reduce the 16 kl lanes. Writes outrow[d] ONCE.
__global__ __launch_bounds__(256) void matvec_k(
    const float* __restrict__ Wv, const float* __restrict__ colsum,
    float* __restrict__ outrow) {
  __shared__ float red[256];
  const int t  = threadIdx.x;
  const int d0 = blockIdx.x * 16;
  const int dl = t & 15;
  const int kl = t >> 4;
  float acc = 0.f;
#pragma unroll 8
  for (int j = 0; j < 64; ++j) {
    const int k = kl + 16 * j;
    acc += colsum[k] * Wv[(size_t)k * DDIM + (d0 + dl)];
  }
  red[t] = acc;
  __syncthreads();
  if (t < 128) red[t] += red[t + 128];
  __syncthreads();
  if (t < 64)  red[t] += red[t + 64];
  __syncthreads();
  if (t < 32)  red[t] += red[t + 32];
  __syncthreads();
  if (t < 16)  outrow[d0 + t] = red[t] + red[t + 16];
}

// K4: broadcast outrow into all rows. 2048 blocks, 4 rows/block, float4 stores.
__global__ __launch_bounds__(256) void bcast_k(
    const float4* __restrict__ outrow4, float4* __restrict__ out4) {
  const int t = threadIdx.x;
  const int b = blockIdx.x;
  const float4 v = outrow4[t];
  float4* p = out4 + (size_t)b * 4 * (DDIM / 4) + t;
#pragma unroll
  for (int r = 0; r < 4; ++r) {
    p[(size_t)r * (DDIM / 4)] = v;
  }
}

extern "C" void kernel_launch(void* const* d_in, const int* in_sizes, int n_in,
                              void* d_out, int out_size, void* d_ws, size_t ws_size,
                              hipStream_t stream) {
  const float* x  = (const float*)d_in[0];
  // d_in[1] = Wq, d_in[2] = Wk provably unused (softmax exactly uniform).
  const float* Wv = (const float*)d_in[3];
  float* ws      = (float*)d_ws;
  float* partial = ws;                         // 1024*1024 floats (4 MB)
  float* colsum  = ws + (size_t)1024 * DDIM;   // 1024 floats
  float* outrow  = colsum + DDIM;              // 1024 floats

  hipLaunchKernelGGL(colsum_part_k, dim3(1024), dim3(256), 0, stream,
                     (const float4*)x, (float4*)partial);
  hipLaunchKernelGGL(colsum_red_k, dim3(64), dim3(256), 0, stream,
                     partial, colsum);
  hipLaunchKernelGGL(matvec_k, dim3(64), dim3(256), 0, stream,
                     Wv, colsum, outrow);
  hipLaunchKernelGGL(bcast_k, dim3(2048), dim3(256), 0, stream,
                     (const float4*)outrow, (float4*)d_out);
}

// Round 5
// 101.933 us; speedup vs baseline: 3.9115x; 1.0094x over previous
//
#include <hip/hip_runtime.h>

// out[i,:] = mean_j(x[j,:]) @ Wv for all i (softmax with 2^-50 scale is exactly
// uniform in fp32; exp(|s|<6e-13) == 1.0f exactly). Q/K/Wq/Wk are dead.
//
// R2: grid.sync() ~100us each -> stream-ordered kernels.
// R3: global same-address atomicAdd ~100ns serialized -> zero atomics, tree reduce.
// R4: dur_us carries a fixed ~85us of harness 256-MiB d_ws poison fills
//     (2 x 42us fillBuffer in the timed window). Controllable part ~18us vs
//     ~13us traffic floor. This round: 4 kernels -> 3 (fuse reduce+matvec) by
//     shrinking the partial buffer to [64][1024] (256 KB).

#define NROWS 8192
#define DDIM  1024
#define D4    (DDIM / 4)   // 256 float4 groups per row

__device__ inline float4 f4add(float4 a, float4 b) {
  return make_float4(a.x + b.x, a.y + b.y, a.z + b.z, a.w + b.w);
}

// K1: partial column sums. 1024 blocks = 64 rowgroups x 16 colgroups.
// Block (rg,cg) sums rows [128rg,128rg+128) over cols [64cg,64cg+64).
// Thread (rl=t>>4, cl=t&15) strides 16 rows, one float4 col-group -> 8 loads.
// Wave = 4 rows x 16 lanes: 4 contiguous 256B segments -> coalesced.
__global__ __launch_bounds__(256) void colsum_part_k(
    const float4* __restrict__ x4, float4* __restrict__ partial4) {
  __shared__ float4 red[256];
  const int t  = threadIdx.x;
  const int rg = blockIdx.x >> 4;   // [0,64)
  const int cg = blockIdx.x & 15;   // [0,16)
  const int cl = t & 15;
  const int rl = t >> 4;            // [0,16)
  const float4* p = x4 + (size_t)(128 * rg + rl) * D4 + 16 * cg + cl;
  float4 acc = make_float4(0.f, 0.f, 0.f, 0.f);
#pragma unroll
  for (int j = 0; j < 8; ++j) {
    acc = f4add(acc, p[(size_t)(16 * j) * D4]);
  }
  red[t] = acc;                      // layout t = rl*16 + cl
  __syncthreads();
  if (t < 128) red[t] = f4add(red[t], red[t + 128]);
  __syncthreads();
  if (t < 64)  red[t] = f4add(red[t], red[t + 64]);
  __syncthreads();
  if (t < 32)  red[t] = f4add(red[t], red[t + 32]);
  __syncthreads();
  if (t < 16)  partial4[(size_t)rg * D4 + 16 * cg + t] = f4add(red[t], red[t + 16]);
}

// K2: fused reduce + matvec. 64 blocks; block i owns d in [16i,16i+16).
// Step 1: all 256 threads reduce partial[64][1024] -> colsum/NROWS in LDS
//         (thread t owns float4 group t; 64 coalesced full-row loads, L2/L3-hot).
// Step 2: thread (kl=t>>4, dl=t&15) accumulates depth-64 over k, LDS broadcast
//         reads (16 lanes same addr = free), then 16-way LDS reduce.
// outrow[d] written exactly once.
__global__ __launch_bounds__(256) void matvec_k(
    const float4* __restrict__ partial4, const float* __restrict__ Wv,
    float* __restrict__ outrow) {
  __shared__ float4 cs4[D4];    // colsum * (1/NROWS), 4 KB
  __shared__ float red[256];
  const int t  = threadIdx.x;
  const int d0 = blockIdx.x * 16;

  float4 acc = make_float4(0.f, 0.f, 0.f, 0.f);
#pragma unroll 8
  for (int r = 0; r < 64; ++r) {
    acc = f4add(acc, partial4[(size_t)r * D4 + t]);
  }
  const float s = 1.0f / (float)NROWS;
  cs4[t] = make_float4(acc.x * s, acc.y * s, acc.z * s, acc.w * s);
  __syncthreads();

  const float* cs = (const float*)cs4;
  const int kl = t >> 4;   // [0,16)
  const int dl = t & 15;
  float a = 0.f;
#pragma unroll 8
  for (int j = 0; j < 64; ++j) {
    const int k = kl + 16 * j;
    a += cs[k] * Wv[(size_t)k * DDIM + d0 + dl];
  }
  red[t] = a;               // layout t = kl*16 + dl
  __syncthreads();
  if (t < 128) red[t] += red[t + 128];
  __syncthreads();
  if (t < 64)  red[t] += red[t + 64];
  __syncthreads();
  if (t < 32)  red[t] += red[t + 32];
  __syncthreads();
  if (t < 16)  outrow[d0 + t] = red[t] + red[t + 16];
}

// K3: broadcast outrow into all rows. 2048 blocks, 4 rows/block, float4 stores.
__global__ __launch_bounds__(256) void bcast_k(
    const float4* __restrict__ outrow4, float4* __restrict__ out4) {
  const int t = threadIdx.x;
  const int b = blockIdx.x;
  const float4 v = outrow4[t];
  float4* p = out4 + (size_t)b * 4 * D4 + t;
#pragma unroll
  for (int r = 0; r < 4; ++r) {
    p[(size_t)r * D4] = v;
  }
}

extern "C" void kernel_launch(void* const* d_in, const int* in_sizes, int n_in,
                              void* d_out, int out_size, void* d_ws, size_t ws_size,
                              hipStream_t stream) {
  const float* x  = (const float*)d_in[0];
  // d_in[1] = Wq, d_in[2] = Wk provably unused (softmax exactly uniform).
  const float* Wv = (const float*)d_in[3];
  float* ws      = (float*)d_ws;
  float* partial = ws;                       // 64*1024 floats (256 KB)
  float* outrow  = ws + (size_t)64 * DDIM;   // 1024 floats

  hipLaunchKernelGGL(colsum_part_k, dim3(1024), dim3(256), 0, stream,
                     (const float4*)x, (float4*)partial);
  hipLaunchKernelGGL(matvec_k, dim3(64), dim3(256), 0, stream,
                     (const float4*)partial, Wv, outrow);
  hipLaunchKernelGGL(bcast_k, dim3(2048), dim3(256), 0, stream,
                     (const float4*)outrow, (float4*)d_out);
}